// Round 9
// baseline (139.809 us; speedup 1.0000x reference)
//
#include <hip/hip_runtime.h>
#include <math.h>

#define N_ROWS 32768
#define K_CODES 4096
#define DIM 64
#define SPLITS 4
#define TILES_TOTAL (K_CODES / 32)              // 128
#define TILES_PER_SPLIT (TILES_TOTAL / SPLITS)  // 32
#define QUANT_ELEMS (N_ROWS * DIM)              // 2097152

typedef _Float16 half8 __attribute__((ext_vector_type(8)));
typedef float floatx16 __attribute__((ext_vector_type(16)));

// async global->LDS, 16 B per lane (wave-uniform base + lane*16 layout)
__device__ __forceinline__ void gld16(const void* g, void* l) {
    __builtin_amdgcn_global_load_lds(
        (const __attribute__((address_space(1))) unsigned int*)g,
        (__attribute__((address_space(3))) unsigned int*)l, 16, 0, 0);
}

// ---------------------------------------------------------------------------
// Kernel 0 (fused): embed -> fp16 hi/lo B-fragments for mfma_f32_32x32x16_f16
// AND per-code squared norms (LDS reduction) AND zero-init of the per-row
// argmax keys (grid is exactly N_ROWS threads).
// Tile c = 32 codes; kstep s covers k=16s..16s+15. Thread t = c*256 + s*64 + l
// holds B[k=(l>>5)*8+j+16s][col=l&31] = embed[c*32+(l&31)][(l>>5)*8+j+16s].
// One 256-thread block per tile (grid = 128 blocks).
// ---------------------------------------------------------------------------
__global__ void prep_kernel(const float* __restrict__ embed,
                            float* __restrict__ sq, half8* __restrict__ ehi,
                            half8* __restrict__ elo,
                            unsigned long long* __restrict__ keys) {
    __shared__ float part[256];
    const int tid = threadIdx.x;
    const int t = blockIdx.x * 256 + tid;
    keys[t] = 0ull;  // any finite packed key beats 0
    const int l = t & 63;
    const int s = (t >> 6) & 3;
    const int c = blockIdx.x;  // == t >> 8
    const int col = l & 31;
    const int code = c * 32 + col;
    const int koff = (l >> 5) * 8 + 16 * s;
    const float* src = embed + (size_t)code * DIM + koff;
    half8 h, lo;
    float ss = 0.f;
#pragma unroll
    for (int j = 0; j < 8; ++j) {
        float v = src[j];
        ss = fmaf(v, v, ss);
        _Float16 hi = (_Float16)v;
        h[j] = hi;
        lo[j] = (_Float16)(v - (float)hi);
    }
    ehi[t] = h;
    elo[t] = lo;
    part[tid] = ss;
    __syncthreads();
    if (tid < 32) {
        // code (c*32 + tid)'s 8 partials live at tid + 32*h + 64*s
        float a = 0.f;
#pragma unroll
        for (int q = 0; q < 8; ++q) a += part[tid + 32 * (q & 1) + 64 * (q >> 1)];
        sq[c * 32 + tid] = a;
    }
}

// ---------------------------------------------------------------------------
// Kernel 1: fused dist(GEMM 32x32x16) + per-split argmax.
// v9: counted-vmcnt fine-phase pipeline (T3+T4 from the measured catalog).
// v2/v8's structure was the 2-phase "stage -> vmcnt(0) drain -> compute"
// lockstep: every phase starts with an LDS-read storm (MFMA idle), then an
// MFMA burst (LDS idle), then a full drain -> dur ~= SUM of pipe demands
// (measured 9.7k cyc/phase vs max-pipe 3.1k). m218's isolated A/B: counted
// vmcnt vs drain-0 = +38-73%.
// New loop: 4-deep LDS ring, prefetch distance 3, ONE tile per barrier:
//   { vmcnt(4) [tile t's own loads retired; t+1..t+3 stay IN FLIGHT across
//     the barrier] -> s_barrier -> issue gld tile t+3 -> 8 ds_read ->
//     12 MFMA (setprio) -> argmax fold }
// vmcnt never drains to 0 until the tail. Buffer-reuse safe: reads of
// buf[(t-1)&3] complete before barrier_t (lgkm dep of t-1's MFMAs); the
// overwrite (gld for t+3) is issued after barrier_t.
// sq panel for the split is cached in LDS (4KB) so the loop has no global
// loads besides the counted gld16s. Loop fully unrolled: all indices and
// vmcnt immediates static.
// dist = dot(2x,e) - ||e||^2 ; -||e||^2 = acc init, 2x folded into A (exact).
// fp16 split, 3 terms: xh*eh + xl*eh + xh*el.
// grid = (N_ROWS/128, SPLITS) = (256, 4) = 1024 blocks = 4/CU, 16 waves/CU.
// LDS 36.9KB/block (4 tile-bufs + sq panel) -> still 4 blocks/CU.
// Cross-split/cross-wave argmax combine via packed-key atomicMax (exact tie
// semantics, validated in v7).
// ---------------------------------------------------------------------------
__global__ __launch_bounds__(256, 4) void fused_dist_argmax32(
    const float* __restrict__ x, const float* __restrict__ sq,
    const half8* __restrict__ ehi, const half8* __restrict__ elo,
    unsigned long long* __restrict__ keys) {
    // 4-deep ring of 8 KB tile buffers: [0,4K)=hi, [4K,8K)=lo
    __shared__ __align__(16) char lbuf[4][8192];
    __shared__ float sqs[TILES_PER_SPLIT * 32];  // this split's ||e||^2 panel

    const int tid = threadIdx.x;
    const int lane = tid & 63;
    const int wave = tid >> 6;
    const int col = lane & 31;    // B col (code within tile); A row
    const int half_ = lane >> 5;  // k-half
    const int row_base = blockIdx.x * 128 + wave * 32;
    const int split = blockIdx.y;
    const int c0 = split * TILES_PER_SPLIT;

    // Persistent A fragments (scaled by 2): A[m=col][k=half_*8+j+16s]
    half8 ah[4], al[4];
    {
        const float* xs = x + (size_t)(row_base + col) * DIM + half_ * 8;
#pragma unroll
        for (int s = 0; s < 4; ++s) {
            half8 h, lo;
#pragma unroll
            for (int j = 0; j < 8; ++j) {
                float v = 2.0f * xs[16 * s + j];
                _Float16 hi = (_Float16)v;
                h[j] = hi;
                lo[j] = (_Float16)(v - (float)hi);
            }
            ah[s] = h;
            al[s] = lo;
        }
    }

    float best[16];
    int bidx[16];
#pragma unroll
    for (int r = 0; r < 16; ++r) {
        best[r] = -INFINITY;
        bidx[r] = 0;
    }

    const char* gh = (const char*)(ehi + (size_t)c0 * 256);
    const char* gl = (const char*)(elo + (size_t)c0 * 256);

    // prologue: sq panel -> LDS (coalesced float4 per thread; 1024 floats),
    // then stage tiles 0..2 into the ring.
    {
        const float4 v = reinterpret_cast<const float4*>(sq + c0 * 32)[tid];
        reinterpret_cast<float4*>(sqs)[tid] = v;
    }
#pragma unroll
    for (int t = 0; t < 3; ++t) {
        char* d = lbuf[t];
        gld16(gh + (size_t)t * 4096 + (size_t)tid * 16, d + tid * 16);
        gld16(gl + (size_t)t * 4096 + (size_t)tid * 16, d + 4096 + tid * 16);
    }

#pragma unroll
    for (int t = 0; t < TILES_PER_SPLIT; ++t) {
        // counted wait: tile t's own 2 loads retired; later tiles in flight.
        if (t < TILES_PER_SPLIT - 2)
            asm volatile("s_waitcnt vmcnt(4)" ::: "memory");
        else if (t == TILES_PER_SPLIT - 2)
            asm volatile("s_waitcnt vmcnt(2)" ::: "memory");
        else
            asm volatile("s_waitcnt vmcnt(0)" ::: "memory");
        __builtin_amdgcn_s_barrier();  // all waves' tile-t loads now visible
        asm volatile("" ::: "memory");

        // prefetch tile t+3 into the ring slot last read at iter t-1
        if (t + 3 < TILES_PER_SPLIT) {
            char* d = lbuf[(t + 3) & 3];
            gld16(gh + (size_t)(t + 3) * 4096 + (size_t)tid * 16, d + tid * 16);
            gld16(gl + (size_t)(t + 3) * 4096 + (size_t)tid * 16,
                  d + 4096 + tid * 16);
        }

        const half8* lh = (const half8*)lbuf[t & 3];
        const half8* ll = (const half8*)(lbuf[t & 3] + 4096);
        const float nsqv = -sqs[t * 32 + col];

        floatx16 acc;
#pragma unroll
        for (int r = 0; r < 16; ++r) acc[r] = nsqv;

        half8 b;
        __builtin_amdgcn_s_setprio(1);
        b = lh[lane];
        acc = __builtin_amdgcn_mfma_f32_32x32x16_f16(ah[0], b, acc, 0, 0, 0);
        acc = __builtin_amdgcn_mfma_f32_32x32x16_f16(al[0], b, acc, 0, 0, 0);
        b = lh[64 + lane];
        acc = __builtin_amdgcn_mfma_f32_32x32x16_f16(ah[1], b, acc, 0, 0, 0);
        acc = __builtin_amdgcn_mfma_f32_32x32x16_f16(al[1], b, acc, 0, 0, 0);
        b = lh[128 + lane];
        acc = __builtin_amdgcn_mfma_f32_32x32x16_f16(ah[2], b, acc, 0, 0, 0);
        acc = __builtin_amdgcn_mfma_f32_32x32x16_f16(al[2], b, acc, 0, 0, 0);
        b = lh[192 + lane];
        acc = __builtin_amdgcn_mfma_f32_32x32x16_f16(ah[3], b, acc, 0, 0, 0);
        acc = __builtin_amdgcn_mfma_f32_32x32x16_f16(al[3], b, acc, 0, 0, 0);
        b = ll[lane];
        acc = __builtin_amdgcn_mfma_f32_32x32x16_f16(ah[0], b, acc, 0, 0, 0);
        b = ll[64 + lane];
        acc = __builtin_amdgcn_mfma_f32_32x32x16_f16(ah[1], b, acc, 0, 0, 0);
        b = ll[128 + lane];
        acc = __builtin_amdgcn_mfma_f32_32x32x16_f16(ah[2], b, acc, 0, 0, 0);
        b = ll[192 + lane];
        acc = __builtin_amdgcn_mfma_f32_32x32x16_f16(ah[3], b, acc, 0, 0, 0);
        __builtin_amdgcn_s_setprio(0);

        const int cidx = (c0 + t) * 32 + col;
#pragma unroll
        for (int r = 0; r < 16; ++r) {
            if (acc[r] > best[r]) {  // strict >: earliest tile wins ties
                best[r] = acc[r];
                bidx[r] = cidx;
            }
        }
    }

    // C/D layout (32x32): col = lane&31, row = (r&3) + 8*(r>>2) + 4*half_.
#pragma unroll
    for (int r = 0; r < 16; ++r) {
        float bv = best[r];
        int bi = bidx[r];
#pragma unroll
        for (int d = 1; d < 32; d <<= 1) {
            float ov = __shfl_xor(bv, d);
            int oi = __shfl_xor(bi, d);
            if (ov > bv || (ov == bv && oi < bi)) {  // smaller idx on tie
                bv = ov;
                bi = oi;
            }
        }
        if (col == 0) {
            const int row = row_base + (r & 3) + 8 * (r >> 2) + 4 * half_;
            // monotone f32 -> u32 map (order-preserving incl. negatives)
            unsigned ub = __float_as_uint(bv);
            unsigned mapped = ub ^ (((int)ub >> 31) | 0x80000000u);
            unsigned long long key =
                ((unsigned long long)mapped << 32) | (unsigned)(~bi);
            atomicMax(keys + row, key);  // equal dist -> larger ~bi = min bi
        }
    }
}

// ---------------------------------------------------------------------------
// Kernel 2: read per-row key, gather quantize row, write index-as-float.
// One thread per (row, float4-chunk): t in [0, N_ROWS*16).
// ---------------------------------------------------------------------------
__global__ void combine_kernel(const unsigned long long* __restrict__ keys,
                               const float* __restrict__ embed,
                               float* __restrict__ out) {
    const int t = blockIdx.x * blockDim.x + threadIdx.x;
    const int row = t >> 4;
    const int q = t & 15;
    if (row >= N_ROWS) return;

    const unsigned long long key = keys[row];
    const int bi = (int)(~(unsigned)key);  // low32 stored as ~idx

    const float4* e4 = reinterpret_cast<const float4*>(embed);
    float4 v = e4[(size_t)bi * (DIM / 4) + q];
    reinterpret_cast<float4*>(out)[(size_t)row * (DIM / 4) + q] = v;
    if (q == 0) {
        out[(size_t)QUANT_ELEMS + row] = (float)bi;  // index as float
    }
}

// ---------------------------------------------------------------------------
extern "C" void kernel_launch(void* const* d_in, const int* in_sizes, int n_in,
                              void* d_out, int out_size, void* d_ws,
                              size_t ws_size, hipStream_t stream) {
    const float* x = (const float*)d_in[0];
    const float* embed = (const float*)d_in[1];
    float* out = (float*)d_out;

    // ws: sq 16KB | ehi 512KB | elo 512KB | keys 256KB   (total ~1.28 MB)
    char* ws = (char*)d_ws;
    float* sq = (float*)ws;
    half8* ehi = (half8*)(ws + 16384);
    half8* elo = (half8*)(ws + 16384 + 524288);
    unsigned long long* keys =
        (unsigned long long*)(ws + 16384 + 2 * 524288);

    prep_kernel<<<TILES_TOTAL, 256, 0, stream>>>(embed, sq, ehi, elo, keys);

    dim3 grid(N_ROWS / 128, SPLITS);
    fused_dist_argmax32<<<grid, 256, 0, stream>>>(x, sq, ehi, elo, keys);

    const int combine_threads = N_ROWS * (DIM / 4);
    combine_kernel<<<(combine_threads + 255) / 256, 256, 0, stream>>>(
        keys, embed, out);
}